// Round 1
// baseline (475.013 us; speedup 1.0000x reference)
//
#include <hip/hip_runtime.h>
#include <hip/hip_bf16.h>

// Problem constants (from reference): F fields, NX x NY valid grid, ghost width 1.
#define F_DIM 4
#define NX 4096
#define NY 4096
#define OX (NX + 2)   // 4098
#define OY (NY + 2)   // 4098
#define OUT_PER_F (OX * OY)            // 16,793,604  (< 2^31, fits uint32)
#define TOTAL (F_DIM * OUT_PER_F)      // 67,174,416  (< 2^31, fits uint32)

// One output element per thread, flat 1D. All index math in 32-bit so the
// divisions by OUT_PER_F / OY compile to magic multiplies.
// Memory behavior:
//  - stores: unit-stride, fully coalesced (dense write of the whole padded array,
//    required anyway since d_out is poisoned 0xAA before every timed launch).
//  - interior loads: unit-stride coalesced (input row j maps to output row j+1,
//    column shifted by +1 -> consecutive threads read consecutive floats).
//  - edge-column loads (y==0 / y==OY-1): strided, but those cache lines are also
//    read by the interior copy -> L2 hits, negligible HBM traffic.
__global__ __launch_bounds__(256) void bc_pad_kernel(
    const float* __restrict__ in,        // (F, NX, NY)
    const float* __restrict__ bc_const,  // (2, 2) [axis, side]
    const float* __restrict__ bc_factor, // (2, 2)
    float* __restrict__ out)             // (F, OX, OY)
{
    unsigned idx = blockIdx.x * 256u + threadIdx.x;
    if (idx >= (unsigned)TOTAL) return;

    unsigned f   = idx / (unsigned)OUT_PER_F;
    unsigned rem = idx - f * (unsigned)OUT_PER_F;
    unsigned x   = rem / (unsigned)OY;
    unsigned y   = rem - x * (unsigned)OY;

    const unsigned f_base = f * (unsigned)(NX * NY);

    bool xin = (x >= 1u) && (x <= (unsigned)NX);
    bool yin = (y >= 1u) && (y <= (unsigned)NY);

    float v;
    if (xin && yin) {
        // interior: plain copy
        v = in[f_base + (x - 1u) * (unsigned)NY + (y - 1u)];
    } else if (yin) {
        // x boundary (axis 0): row 0 -> side 0 (adjacent valid row 0),
        //                      row OX-1 -> side 1 (adjacent valid row NX-1)
        int side = (x != 0u) ? 1 : 0;
        unsigned sx = side ? (unsigned)(NX - 1) : 0u;
        float c  = bc_const[0 * 2 + side];
        float fa = bc_factor[0 * 2 + side];
        v = c + fa * in[f_base + sx * (unsigned)NY + (y - 1u)];
    } else if (xin) {
        // y boundary (axis 1): col 0 -> side 0, col OY-1 -> side 1
        int side = (y != 0u) ? 1 : 0;
        unsigned sy = side ? (unsigned)(NY - 1) : 0u;
        float c  = bc_const[1 * 2 + side];
        float fa = bc_factor[1 * 2 + side];
        v = c + fa * in[f_base + (x - 1u) * (unsigned)NY + sy];
    } else {
        // corners stay zero (jnp.pad semantics; nothing overwrites them)
        v = 0.0f;
    }

    out[idx] = v;
}

extern "C" void kernel_launch(void* const* d_in, const int* in_sizes, int n_in,
                              void* d_out, int out_size, void* d_ws, size_t ws_size,
                              hipStream_t stream) {
    const float* arr       = (const float*)d_in[0];
    const float* bc_const  = (const float*)d_in[1];
    const float* bc_factor = (const float*)d_in[2];
    float* out = (float*)d_out;

    unsigned blocks = (TOTAL + 255u) / 256u;
    bc_pad_kernel<<<dim3(blocks), dim3(256), 0, stream>>>(arr, bc_const, bc_factor, out);
}

// Round 2
// 419.750 us; speedup vs baseline: 1.1317x; 1.1317x over previous
//
#include <hip/hip_runtime.h>
#include <hip/hip_bf16.h>

// Problem constants: F fields, NX x NY valid grid, ghost width 1.
#define F_DIM 4
#define NX 4096
#define NY 4096
#define OX (NX + 2)   // 4098
#define OY (NY + 2)   // 4098
#define OUT_PER_F (OX * OY)            // 16,793,604  (mult of 4)
#define TOTAL (F_DIM * OUT_PER_F)      // 67,174,416  (mult of 4)
#define NVEC (TOTAL / 4)               // 16,793,604 float4s
#define VEC_PER_F (OUT_PER_F / 4)      // 4,198,401 -> vec4 never straddles a field

// Scalar fallback: full decode of one padded-array element (used only on the
// ~0.3% of vec4s that touch an edge or straddle a row boundary).
__device__ __forceinline__ float bc_element(
    const float* __restrict__ in, const float* __restrict__ bc_const,
    const float* __restrict__ bc_factor, unsigned f_base, unsigned x, unsigned y)
{
    bool xin = (x >= 1u) && (x <= (unsigned)NX);
    bool yin = (y >= 1u) && (y <= (unsigned)NY);
    if (xin && yin) {
        return in[f_base + (x - 1u) * (unsigned)NY + (y - 1u)];
    } else if (yin) {
        int side = (x != 0u) ? 1 : 0;
        unsigned sx = side ? (unsigned)(NX - 1) : 0u;
        return bc_const[0 * 2 + side] + bc_factor[0 * 2 + side] * in[f_base + sx * (unsigned)NY + (y - 1u)];
    } else if (xin) {
        int side = (y != 0u) ? 1 : 0;
        unsigned sy = side ? (unsigned)(NY - 1) : 0u;
        return bc_const[1 * 2 + side] + bc_factor[1 * 2 + side] * in[f_base + (x - 1u) * (unsigned)NY + sy];
    }
    return 0.0f;  // corners (jnp.pad zeros)
}

// One thread per 16B-aligned output float4.
//  - stores: global_store_dwordx4, unit-stride coalesced, always 16B aligned
//    (out base aligned, flat index multiple of 4).
//  - fast-path loads: the input offset o = f_base+(x-1)*NY+(y-1) is provably
//    ODD (vidx%4==0 and OY%4==2 force y even; f_base and (x-1)*NY are even),
//    so we split as in[o] (dword) + in[o+1..o+2] (8B-aligned dwordx2) + in[o+3].
__global__ __launch_bounds__(256) void bc_pad_vec4_kernel(
    const float* __restrict__ in,        // (F, NX, NY)
    const float* __restrict__ bc_const,  // (2, 2) [axis, side]
    const float* __restrict__ bc_factor, // (2, 2)
    float* __restrict__ out)             // (F, OX, OY)
{
    unsigned idx = blockIdx.x * 256u + threadIdx.x;
    if (idx >= (unsigned)NVEC) return;

    unsigned f    = idx / (unsigned)VEC_PER_F;
    unsigned vrem = (idx - f * (unsigned)VEC_PER_F) * 4u;  // flat offset within field
    unsigned x    = vrem / (unsigned)OY;
    unsigned y    = vrem - x * (unsigned)OY;
    const unsigned f_base = f * (unsigned)(NX * NY);

    float4 v;
    // Fast path: all 4 elements interior, same row (y..y+3 in [1, NY]).
    if (x >= 1u && x <= (unsigned)NX && y >= 1u && y + 3u <= (unsigned)NY) {
        unsigned o = f_base + (x - 1u) * (unsigned)NY + (y - 1u);  // odd
        float  a  = in[o];
        float2 bc = *reinterpret_cast<const float2*>(&in[o + 1u]); // 8B aligned
        float  d  = in[o + 3u];
        v = make_float4(a, bc.x, bc.y, d);
    } else {
        // Slow path: per-element decode (handles edges, corners, row straddle;
        // never straddles a field since VEC_PER_F is an integer).
        unsigned r0 = vrem;
        float vv[4];
        #pragma unroll
        for (int k = 0; k < 4; ++k) {
            unsigned r  = r0 + (unsigned)k;
            unsigned xx = r / (unsigned)OY;
            unsigned yy = r - xx * (unsigned)OY;
            vv[k] = bc_element(in, bc_const, bc_factor, f_base, xx, yy);
        }
        v = make_float4(vv[0], vv[1], vv[2], vv[3]);
    }

    reinterpret_cast<float4*>(out)[idx] = v;
}

extern "C" void kernel_launch(void* const* d_in, const int* in_sizes, int n_in,
                              void* d_out, int out_size, void* d_ws, size_t ws_size,
                              hipStream_t stream) {
    const float* arr       = (const float*)d_in[0];
    const float* bc_const  = (const float*)d_in[1];
    const float* bc_factor = (const float*)d_in[2];
    float* out = (float*)d_out;

    unsigned blocks = ((unsigned)NVEC + 255u) / 256u;
    bc_pad_vec4_kernel<<<dim3(blocks), dim3(256), 0, stream>>>(arr, bc_const, bc_factor, out);
}